// Round 1
// baseline (16100.652 us; speedup 1.0000x reference)
//
#include <hip/hip_runtime.h>

// Problem constants
#define TSTEPS 512
#define NBATCH 8
#define DDIM   512
#define UDIM   1024
#define VOUT   50257
#define VPAD   50304      // 393 * 128
#define MROWS  4096       // B*T
#define COOP_WGS 192

typedef _Float16 half8 __attribute__((ext_vector_type(8)));
typedef float    floatx4 __attribute__((ext_vector_type(4)));

__device__ __forceinline__ void gl2lds16(const void* g, void* l) {
  __builtin_amdgcn_global_load_lds(
      (const __attribute__((address_space(1))) unsigned int*)g,
      (__attribute__((address_space(3))) unsigned int*)l, 16, 0, 0);
}

// ---------------------------------------------------------------------------
// Convert x[4096,512] fp32 -> A1' = [Xh | Xh | Xl]  [4096,1536] fp16
// ---------------------------------------------------------------------------
__global__ void a1cvt_k(const float* __restrict__ x, _Float16* __restrict__ A1) {
  const int idx = blockIdx.x * 256 + threadIdx.x;   // < 4096*512
  const int m = idx >> 9, k = idx & 511;
  const float v = x[idx];
  const _Float16 h = (_Float16)v;
  const _Float16 l = (_Float16)(v - (float)h);
  const size_t base = (size_t)m * 1536;
  A1[base + k]        = h;
  A1[base + 512 + k]  = h;
  A1[base + 1024 + k] = l;
}

// ---------------------------------------------------------------------------
// Transpose+convert: src[K][Nsrc] fp32 -> dst[n][kofs + k] fp16 (hi or lo part)
// grid = (dst_rows/64, Ksrc/32). Rows n >= Nsrc get zeros (pads B for GEMM).
// ---------------------------------------------------------------------------
__global__ void transcvt_k(const float* __restrict__ src, _Float16* __restrict__ dst,
                           int Nsrc, int LDK, int kofs, int mode) {
  __shared__ _Float16 tl[32][72];
  const int n0 = blockIdx.x * 64, k0 = blockIdx.y * 32;
  const int tid = threadIdx.x;
  {
    const int n = tid & 63, kq = tid >> 6;   // kq 0..3
#pragma unroll
    for (int j = 0; j < 8; ++j) {
      const int k = kq * 8 + j;
      const float v = (n0 + n < Nsrc) ? src[(size_t)(k0 + k) * Nsrc + n0 + n] : 0.f;
      const _Float16 h = (_Float16)v;
      tl[k][n] = mode ? (_Float16)(v - (float)h) : h;
    }
  }
  __syncthreads();
  {
    const int nn = tid >> 2, kc = tid & 3;   // nn 0..63
    half8 pk;
#pragma unroll
    for (int j = 0; j < 8; ++j) pk[j] = tl[kc * 8 + j][nn];
    *(half8*)(dst + (size_t)(n0 + nn) * LDK + kofs + k0 + kc * 8) = pk;
  }
}

// ---------------------------------------------------------------------------
// fp16 MFMA GEMM: C[M,N] = A[M,K] * B[N,K]^T(+bias). 128x128 tile, BK=64.
// grid.x = (N/128)*32, decode mt = bx&31 (M=4096 always), nt = bx>>5.
// EPI=0: C = acc + bias (fp32).  EPI=1: C = exp(acc+bias), rowsums += partials.
// LDS: XOR-swizzled 16B chunks: slot(r,cs) holds global chunk cs^(r&7).
// ---------------------------------------------------------------------------
template <int EPI>
__global__ __launch_bounds__(256, 3)
void gemm_f16_k(const _Float16* __restrict__ A, const _Float16* __restrict__ B,
                const float* __restrict__ bias, float* __restrict__ C,
                float* __restrict__ rowsums, int K, int Nvalid, int ldc) {
  __shared__ _Float16 sA[128 * 64];
  __shared__ _Float16 sB[128 * 64];
  __shared__ float rsl[128];
  const int bx = blockIdx.x;
  const int mt = bx & 31, nt = bx >> 5;
  const int m0 = mt << 7, n0 = nt << 7;
  const int tid = threadIdx.x;
  const int lane = tid & 63;
  const int wv = __builtin_amdgcn_readfirstlane(tid >> 6);
  const int wm = wv & 1, wn = wv >> 1;

  floatx4 acc[4][4];
#pragma unroll
  for (int i = 0; i < 4; ++i)
#pragma unroll
    for (int j = 0; j < 4; ++j)
#pragma unroll
      for (int r = 0; r < 4; ++r) acc[i][j][r] = 0.f;

  const int kiters = K >> 6;
  for (int kk = 0; kk < kiters; ++kk) {
    const int k0 = kk << 6;
#pragma unroll
    for (int i = 0; i < 4; ++i) {
      const int s = (wv << 8) + (i << 6) + lane;
      const int r = s >> 3;
      const int cg = (s & 7) ^ (r & 7);
      gl2lds16(A + (size_t)(m0 + r) * K + (k0 + (cg << 3)),
               sA + (size_t)((wv << 8) + (i << 6)) * 8);
      gl2lds16(B + (size_t)(n0 + r) * K + (k0 + (cg << 3)),
               sB + (size_t)((wv << 8) + (i << 6)) * 8);
    }
    __syncthreads();
    const int q = lane >> 4, li = lane & 15;
#pragma unroll
    for (int s2 = 0; s2 < 2; ++s2) {
      half8 af[4], bf[4];
#pragma unroll
      for (int mi = 0; mi < 4; ++mi) {
        const int r = (wm << 6) + (mi << 4) + li;
        const int cg = (s2 << 2) + q;
        af[mi] = *(const half8*)(sA + (size_t)((r << 3) + (cg ^ (r & 7))) * 8);
      }
#pragma unroll
      for (int ni = 0; ni < 4; ++ni) {
        const int r = (wn << 6) + (ni << 4) + li;
        const int cg = (s2 << 2) + q;
        bf[ni] = *(const half8*)(sB + (size_t)((r << 3) + (cg ^ (r & 7))) * 8);
      }
#pragma unroll
      for (int mi = 0; mi < 4; ++mi)
#pragma unroll
        for (int ni = 0; ni < 4; ++ni)
          acc[mi][ni] = __builtin_amdgcn_mfma_f32_16x16x32_f16(af[mi], bf[ni], acc[mi][ni], 0, 0, 0);
    }
    __syncthreads();
  }

  if (EPI == 1 && tid < 128) rsl[tid] = 0.f;
  __syncthreads();

  const int q = lane >> 4, li = lane & 15;
#pragma unroll
  for (int ni = 0; ni < 4; ++ni) {
    const int n = n0 + (wn << 6) + (ni << 4) + li;
    const bool nv = (n < Nvalid);
    const float bv = nv ? bias[n] : 0.f;
#pragma unroll
    for (int mi = 0; mi < 4; ++mi) {
      const int mb = m0 + (wm << 6) + (mi << 4) + (q << 2);
      float vr[4];
#pragma unroll
      for (int r = 0; r < 4; ++r) {
        float v = acc[mi][ni][r] + bv;
        if (EPI == 1) v = __expf(v);
        if (nv) C[(size_t)(mb + r) * ldc + n] = v;
        vr[r] = nv ? v : 0.f;
      }
      if (EPI == 1) {
#pragma unroll
        for (int r = 0; r < 4; ++r) {
          vr[r] += __shfl_xor(vr[r], 1, 64);
          vr[r] += __shfl_xor(vr[r], 2, 64);
          vr[r] += __shfl_xor(vr[r], 4, 64);
          vr[r] += __shfl_xor(vr[r], 8, 64);
        }
        if (li == 0) {
          const int lrow = (wm << 6) + (mi << 4) + (q << 2);
#pragma unroll
          for (int r = 0; r < 4; ++r) atomicAdd(&rsl[lrow + r], vr[r]);
        }
      }
    }
  }
  if (EPI == 1) {
    __syncthreads();
    if (tid < 128) atomicAdd(&rowsums[m0 + tid], rsl[tid]);
  }
}

// ---------------------------------------------------------------------------
// Cooperative recurrence kernel. 192 WGs x 256 threads, 513 iterations.
// WG 0..63  : layer1, 16 cols each:  h1[t] = tanh(Xp1[t] + h1[t-1]@Wh1)
// WG 64..191: layer2, 8 cols each:   h2[t-1] = tanh(h1[t-1]@Wx2 + h2[t-2]@Wh2 + b2)
// (layer2 runs one step behind -> single grid barrier per iteration)
// Thread map: tid = bg(1) | cg(2) | kg(5). k interleaved (k = kg*2 + 64j + {0,1}).
// Dynamic LDS: Wl[16*1024] | hbufA[8192] | hbufB[8192] | pbuf[128] floats.
// ---------------------------------------------------------------------------
__global__ __launch_bounds__(256)
void rnn_coop_k(const float* __restrict__ Xp1, const float* __restrict__ Wh1,
                const float* __restrict__ Wx2, const float* __restrict__ Wh2,
                const float* __restrict__ b2,
                float* __restrict__ H1, float* __restrict__ H2s,
                _Float16* __restrict__ H2f,
                unsigned long long* __restrict__ ctrs) {
  extern __shared__ float smem[];
  float* Wl    = smem;            // 16384 floats (64KB)
  float* hbufA = smem + 16384;    // 8192 floats (32KB)
  float* hbufB = smem + 24576;    // 8192 floats (32KB)
  float* pbuf  = smem + 32768;    // 128 floats

  const int wg = blockIdx.x;
  const bool isL1 = (wg < 64);
  const int tid = threadIdx.x;

  // Load weight slices into LDS (once).
  if (isL1) {
    const int n0 = wg << 4;
    for (int idx = tid; idx < 16 * 1024; idx += 256) {
      const int k = idx >> 4, c = idx & 15;
      Wl[c * 1024 + k] = Wh1[(size_t)k * 1024 + n0 + c];
    }
  } else {
    const int n0 = (wg - 64) << 3;
    for (int idx = tid; idx < 8 * 1024; idx += 256) {
      const int k = idx >> 3, c = idx & 7;
      Wl[c * 1024 + k]       = Wx2[(size_t)k * 1024 + n0 + c];
      Wl[(8 + c) * 1024 + k] = Wh2[(size_t)k * 1024 + n0 + c];
    }
  }

  const int kg = tid & 31, cg = (tid >> 5) & 3, bg = tid >> 7;
  const float* hA_sel = (!isL1 && cg >= 2) ? hbufB : hbufA;

  for (int t = 0; t <= TSTEPS; ++t) {
    const bool active = isL1 ? (t < TSTEPS) : (t >= 1);
    if (active) {
      const int ta = t - 1;
      if (isL1) {
        if (ta >= 0) {
          const float4* s = (const float4*)(H1 + (size_t)ta * 8192);
          for (int i = tid; i < 2048; i += 256) ((float4*)hbufA)[i] = s[i];
        } else {
          const float4 z = make_float4(0.f, 0.f, 0.f, 0.f);
          for (int i = tid; i < 2048; i += 256) ((float4*)hbufA)[i] = z;
        }
      } else {
        const float4* s = (const float4*)(H1 + (size_t)ta * 8192);
        for (int i = tid; i < 2048; i += 256) ((float4*)hbufA)[i] = s[i];
        const int tb = t - 2;
        if (tb >= 0) {
          const float4* s2 = (const float4*)(H2s + (size_t)tb * 8192);
          for (int i = tid; i < 2048; i += 256) ((float4*)hbufB)[i] = s2[i];
        } else {
          const float4 z = make_float4(0.f, 0.f, 0.f, 0.f);
          for (int i = tid; i < 2048; i += 256) ((float4*)hbufB)[i] = z;
        }
      }
    }
    __syncthreads();  // covers Wl on first iteration + hbuf staging

    if (active) {
      float av[4][4];
#pragma unroll
      for (int b = 0; b < 4; ++b)
#pragma unroll
        for (int i = 0; i < 4; ++i) av[b][i] = 0.f;
#pragma unroll 4
      for (int j = 0; j < 16; ++j) {
        const int k0 = (kg << 1) + (j << 6);
        float2 hv[4], wvec[4];
#pragma unroll
        for (int b = 0; b < 4; ++b)
          hv[b] = *(const float2*)(hA_sel + ((bg << 2) + b) * 1024 + k0);
#pragma unroll
        for (int i = 0; i < 4; ++i)
          wvec[i] = *(const float2*)(Wl + ((cg << 2) + i) * 1024 + k0);
#pragma unroll
        for (int b = 0; b < 4; ++b)
#pragma unroll
          for (int i = 0; i < 4; ++i)
            av[b][i] += hv[b].x * wvec[i].x + hv[b].y * wvec[i].y;
      }
      // reduce across the 32 kg lanes (butterfly, stays within 32-lane half)
#pragma unroll
      for (int b = 0; b < 4; ++b)
#pragma unroll
        for (int i = 0; i < 4; ++i) {
          float v = av[b][i];
          v += __shfl_xor(v, 1, 64);
          v += __shfl_xor(v, 2, 64);
          v += __shfl_xor(v, 4, 64);
          v += __shfl_xor(v, 8, 64);
          v += __shfl_xor(v, 16, 64);
          av[b][i] = v;
        }
      if (isL1) {
        if (kg == 0) {
          const int n0 = wg << 4;
#pragma unroll
          for (int b = 0; b < 4; ++b)
#pragma unroll
            for (int i = 0; i < 4; ++i) {
              const int bb = (bg << 2) + b;
              const int n = n0 + (cg << 2) + i;
              const float pre = av[b][i] + Xp1[((size_t)bb * TSTEPS + t) * 1024 + n];
              H1[(size_t)t * 8192 + bb * 1024 + n] = tanhf(pre);
            }
        }
      } else {
        if (kg == 0) {
#pragma unroll
          for (int b = 0; b < 4; ++b)
#pragma unroll
            for (int i = 0; i < 4; ++i)
              pbuf[((cg << 2) + i) * 8 + (bg << 2) + b] = av[b][i];
        }
        __syncthreads();
        if (tid < 64) {
          const int c = tid & 7, b = tid >> 3;
          const int n = ((wg - 64) << 3) + c;
          const int tt = t - 1;
          const float pre = pbuf[c * 8 + b] + pbuf[(c + 8) * 8 + b] + b2[n];
          const float h = tanhf(pre);
          H2s[(size_t)tt * 8192 + b * 1024 + n] = h;
          H2f[((size_t)b * TSTEPS + tt) * 1024 + n] = (_Float16)h;
        }
      }
    }

    // ---- grid barrier (monotonic 8-counter, device scope) ----
    __syncthreads();  // all WG stores issued (syncthreads drains vmcnt)
    if (tid == 0) {
      __threadfence();  // publish this WG's global writes device-wide
      __hip_atomic_fetch_add(&ctrs[wg & 7], 1ull, __ATOMIC_RELAXED, __HIP_MEMORY_SCOPE_AGENT);
      const unsigned long long target =
          (unsigned long long)(t + 1) * (unsigned long long)COOP_WGS;
      for (;;) {
        unsigned long long ssum = 0;
#pragma unroll
        for (int i = 0; i < 8; ++i)
          ssum += __hip_atomic_load(&ctrs[i], __ATOMIC_RELAXED, __HIP_MEMORY_SCOPE_AGENT);
        if (ssum >= target) break;
        __builtin_amdgcn_s_sleep(2);
      }
      __threadfence();  // acquire: invalidate stale L1/L2 before next iter's reads
    }
    __syncthreads();
  }
}

// ---------------------------------------------------------------------------
// out[row, :] *= 1/rowsum[row]
// ---------------------------------------------------------------------------
__global__ void norm_k(float* __restrict__ C, const float* __restrict__ rs, int N) {
  const int row = blockIdx.y;
  const float inv = 1.0f / rs[row];
  const size_t rb = (size_t)row * N;
  const int c0 = blockIdx.x * 1024 + threadIdx.x;
#pragma unroll
  for (int j = 0; j < 4; ++j) {
    const int c = c0 + j * 256;
    if (c < N) C[rb + c] *= inv;
  }
}

// ---------------------------------------------------------------------------
extern "C" void kernel_launch(void* const* d_in, const int* in_sizes, int n_in,
                              void* d_out, int out_size, void* d_ws, size_t ws_size,
                              hipStream_t stream) {
  const float* x    = (const float*)d_in[0];
  const float* Wx1  = (const float*)d_in[1];
  const float* Wh1  = (const float*)d_in[2];
  const float* b1   = (const float*)d_in[3];
  const float* Wx2  = (const float*)d_in[4];
  const float* Wh2  = (const float*)d_in[5];
  const float* b2   = (const float*)d_in[6];
  const float* Wout = (const float*)d_in[7];
  const float* bout = (const float*)d_in[8];
  float* out = (float*)d_out;

  char* ws = (char*)d_ws;
  size_t off = 0;
  auto alloc = [&](size_t bytes) -> void* {
    off = (off + 255) & ~(size_t)255;
    void* p = ws + off;
    off += bytes;
    return p;
  };
  _Float16* A1h = (_Float16*)alloc((size_t)MROWS * 1536 * 2);   // 12.6 MB
  _Float16* B1t = (_Float16*)alloc((size_t)1024 * 1536 * 2);    // 3.1 MB
  float*    Xp1 = (float*)alloc((size_t)MROWS * 1024 * 4);      // 16.8 MB
  float*    H1  = (float*)alloc((size_t)TSTEPS * 8192 * 4);     // 16.8 MB
  float*    H2s = (float*)alloc((size_t)TSTEPS * 8192 * 4);     // 16.8 MB
  _Float16* H2f = (_Float16*)alloc((size_t)MROWS * 1024 * 2);   // 8.4 MB
  _Float16* BtO = (_Float16*)alloc((size_t)VPAD * 1024 * 2);    // 103 MB
  float*    rsums = (float*)alloc((size_t)MROWS * 4);
  unsigned long long* ctrs = (unsigned long long*)alloc(64);
  // total ~178 MB of d_ws

  hipMemsetAsync(ctrs, 0, 64, stream);
  hipMemsetAsync(rsums, 0, (size_t)MROWS * 4, stream);

  // 1) converts
  a1cvt_k<<<(MROWS * DDIM) / 256, 256, 0, stream>>>(x, A1h);
  transcvt_k<<<dim3(16, 16), 256, 0, stream>>>(Wx1, B1t, 1024, 1536, 0, 0);     // hi
  transcvt_k<<<dim3(16, 16), 256, 0, stream>>>(Wx1, B1t, 1024, 1536, 512, 1);   // lo
  transcvt_k<<<dim3(16, 16), 256, 0, stream>>>(Wx1, B1t, 1024, 1536, 1024, 0);  // hi
  transcvt_k<<<dim3(VPAD / 64, 32), 256, 0, stream>>>(Wout, BtO, VOUT, 1024, 0, 0);

  // 2) Xp1 = [Xh|Xh|Xl] @ [W1h;W1l;W1h] + b1   (fp32-quality via split-fp16)
  gemm_f16_k<0><<<(1024 / 128) * 32, 256, 0, stream>>>(A1h, B1t, b1, Xp1, nullptr,
                                                       1536, 1024, 1024);

  // 3) cooperative recurrence
  const size_t smem_bytes = (size_t)(16384 + 8192 + 8192 + 128) * 4;  // 131584
  hipFuncSetAttribute((const void*)rnn_coop_k,
                      hipFuncAttributeMaxDynamicSharedMemorySize, (int)smem_bytes);
  {
    const float* a0 = Xp1; const float* a1 = Wh1; const float* a2 = Wx2;
    const float* a3 = Wh2; const float* a4 = b2;
    float* a5 = H1; float* a6 = H2s; _Float16* a7 = H2f;
    unsigned long long* a8 = ctrs;
    void* kargs[] = {&a0, &a1, &a2, &a3, &a4, &a5, &a6, &a7, &a8};
    hipError_t ce = hipLaunchCooperativeKernel((const void*)rnn_coop_k,
                                               dim3(COOP_WGS), dim3(256), kargs,
                                               (unsigned)smem_bytes, stream);
    if (ce != hipSuccess) {
      (void)hipGetLastError();
      // 192 WGs @ 132KB LDS -> 1 WG/CU, 192 < 256 CUs: co-resident in practice
      rnn_coop_k<<<COOP_WGS, 256, smem_bytes, stream>>>(Xp1, Wh1, Wx2, Wh2, b2,
                                                        H1, H2s, H2f, ctrs);
    }
  }

  // 4) head GEMM: out = exp(H2 @ Wout^T + bout), rowsums accumulated
  gemm_f16_k<1><<<(VPAD / 128) * 32, 256, 0, stream>>>(H2f, BtO, bout, out, rsums,
                                                       1024, VOUT, VOUT);

  // 5) normalize
  norm_k<<<dim3(50, MROWS), 256, 0, stream>>>(out, rsums, VOUT);
}